// Round 1
// baseline (920.895 us; speedup 1.0000x reference)
//
#include <hip/hip_runtime.h>
#include <math.h>

// Problem constants (reference: B=4, S=2048, E=384, H=8, D=48)
#define B_ 4
#define S_ 2048
#define E_ 384
#define H_ 8
#define D_ 48
#define M_ (B_*S_)            // 8192 rows
constexpr float SCALE = 0.14433756729740643f;   // 1/sqrt(48)

// ---------------------------------------------------------------------------
// GEMM: C[M,384] = A[M,384] @ W[384,384]^T + bias   (C row n uses W row n)
// 64x64 tile, BK=16, 4x4 micro-tile per thread, 256 threads.
// ---------------------------------------------------------------------------
__global__ __launch_bounds__(256) void gemm64(const float* __restrict__ A,
                                              const float* __restrict__ W,
                                              const float* __restrict__ bias,
                                              float* __restrict__ C) {
    __shared__ __align__(16) float As[16][68];   // [k][m], pad 68: 272B rows, 16B-aligned
    __shared__ __align__(16) float Bs[16][68];   // [k][n]
    const int t  = threadIdx.x;
    const int tx = t & 15, ty = t >> 4;
    const int m0 = blockIdx.x * 64, n0 = blockIdx.y * 64;
    const int lm = t >> 2;          // 0..63 : row loaded by this thread
    const int lk = (t & 3) * 4;     // k sub-offset (float4)

    float acc[4][4] = {};

    for (int kk = 0; kk < 384; kk += 16) {
        float4 a = *reinterpret_cast<const float4*>(A + (size_t)(m0 + lm) * 384 + kk + lk);
        float4 w = *reinterpret_cast<const float4*>(W + (size_t)(n0 + lm) * 384 + kk + lk);
        __syncthreads();            // previous iter's readers done
        As[lk + 0][lm] = a.x; As[lk + 1][lm] = a.y;
        As[lk + 2][lm] = a.z; As[lk + 3][lm] = a.w;
        Bs[lk + 0][lm] = w.x; Bs[lk + 1][lm] = w.y;
        Bs[lk + 2][lm] = w.z; Bs[lk + 3][lm] = w.w;
        __syncthreads();
        #pragma unroll
        for (int k = 0; k < 16; ++k) {
            float4 av = *reinterpret_cast<const float4*>(&As[k][ty * 4]);
            float4 bv = *reinterpret_cast<const float4*>(&Bs[k][tx * 4]);
            float aa[4] = {av.x, av.y, av.z, av.w};
            float bb[4] = {bv.x, bv.y, bv.z, bv.w};
            #pragma unroll
            for (int i = 0; i < 4; ++i)
                #pragma unroll
                for (int j = 0; j < 4; ++j)
                    acc[i][j] = fmaf(aa[i], bb[j], acc[i][j]);
        }
    }

    #pragma unroll
    for (int i = 0; i < 4; ++i) {
        float4 o;
        o.x = acc[i][0] + bias[n0 + tx * 4 + 0];
        o.y = acc[i][1] + bias[n0 + tx * 4 + 1];
        o.z = acc[i][2] + bias[n0 + tx * 4 + 2];
        o.w = acc[i][3] + bias[n0 + tx * 4 + 3];
        *reinterpret_cast<float4*>(C + (size_t)(m0 + ty * 4 + i) * 384 + n0 + tx * 4) = o;
    }
}

// ---------------------------------------------------------------------------
// Flash attention, fp32. Block = 256 threads handles 64 q-rows of one (b,h).
// K/V tiles of 64 keys staged in LDS; online softmax via 16-lane shuffles.
// mask semantics (per reference): mask==true -> score = -inf (masked OUT).
// ---------------------------------------------------------------------------
__global__ __launch_bounds__(256) void attn(const float* __restrict__ Qg,
                                            const float* __restrict__ Kg,
                                            const float* __restrict__ Vg,
                                            const int*   __restrict__ mask,
                                            float* __restrict__ AO) {
    __shared__ __align__(16) float Qt[48][68];   // [d][r]
    __shared__ __align__(16) float Kt[48][68];   // [d][j]
    __shared__ __align__(16) float Vs[64][48];   // [j][c]
    __shared__ __align__(16) float Ps[64][68];   // [r][j]
    __shared__ float alphas[64];
    __shared__ float ls[64];
    __shared__ int   ms[64];

    const int t  = threadIdx.x;
    const int tx = t & 15, ty = t >> 4;          // score-role: rows ty*4+i, cols tx*4+jj
    const int q0 = blockIdx.x * 64;
    const int bh = blockIdx.y;
    const int b  = bh >> 3, h = bh & 7;
    const size_t base = (size_t)b * S_ * E_ + (size_t)h * D_;

    // Load Q tile (transposed)
    for (int i = t; i < 64 * 48; i += 256) {
        int r = i / 48, d = i - r * 48;
        Qt[d][r] = Qg[base + (size_t)(q0 + r) * E_ + d];
    }

    const int r_o = t >> 2;            // O-role: row
    const int c0  = (t & 3) * 12;      // O-role: 12 columns
    float o[12] = {};
    float m_i[4], l_i[4];
    #pragma unroll
    for (int i = 0; i < 4; ++i) { m_i[i] = -1e30f; l_i[i] = 0.f; }

    for (int kt = 0; kt < S_ / 64; ++kt) {
        const int k0 = kt * 64;
        __syncthreads();               // prior readers of Kt/Vs/ms done
        for (int i = t; i < 64 * 48; i += 256) {
            int j = i / 48, d = i - j * 48;
            Kt[d][j] = Kg[base + (size_t)(k0 + j) * E_ + d];
            Vs[j][d] = Vg[base + (size_t)(k0 + j) * E_ + d];
        }
        if (t < 64) ms[t] = mask[b * S_ + k0 + t];
        __syncthreads();

        // ---- scores: s[i][jj] = Q[ty*4+i] . K[tx*4+jj] ----
        float s[4][4] = {};
        #pragma unroll 8
        for (int d = 0; d < 48; ++d) {
            float4 av = *reinterpret_cast<const float4*>(&Qt[d][ty * 4]);
            float4 bv = *reinterpret_cast<const float4*>(&Kt[d][tx * 4]);
            float aa[4] = {av.x, av.y, av.z, av.w};
            float bb[4] = {bv.x, bv.y, bv.z, bv.w};
            #pragma unroll
            for (int i = 0; i < 4; ++i)
                #pragma unroll
                for (int jj = 0; jj < 4; ++jj)
                    s[i][jj] = fmaf(aa[i], bb[jj], s[i][jj]);
        }
        int mk[4];
        #pragma unroll
        for (int jj = 0; jj < 4; ++jj) mk[jj] = ms[tx * 4 + jj];

        // ---- online softmax per row (16-lane groups share a row) ----
        #pragma unroll
        for (int i = 0; i < 4; ++i) {
            float sv[4];
            #pragma unroll
            for (int jj = 0; jj < 4; ++jj)
                sv[jj] = mk[jj] ? -1e30f : s[i][jj] * SCALE;
            float lmax = fmaxf(fmaxf(sv[0], sv[1]), fmaxf(sv[2], sv[3]));
            lmax = fmaxf(lmax, __shfl_xor(lmax, 1));
            lmax = fmaxf(lmax, __shfl_xor(lmax, 2));
            lmax = fmaxf(lmax, __shfl_xor(lmax, 4));
            lmax = fmaxf(lmax, __shfl_xor(lmax, 8));
            float mnew  = fmaxf(m_i[i], lmax);
            float alpha = __expf(m_i[i] - mnew);   // m=-1e30,mnew=-1e30 -> 1, but l stays 0
            float p[4], psum = 0.f;
            #pragma unroll
            for (int jj = 0; jj < 4; ++jj) {
                p[jj] = (sv[jj] < -1e29f) ? 0.f : __expf(sv[jj] - mnew);
                psum += p[jj];
            }
            psum += __shfl_xor(psum, 1);
            psum += __shfl_xor(psum, 2);
            psum += __shfl_xor(psum, 4);
            psum += __shfl_xor(psum, 8);
            l_i[i] = l_i[i] * alpha + psum;
            m_i[i] = mnew;
            float4 pv = make_float4(p[0], p[1], p[2], p[3]);
            *reinterpret_cast<float4*>(&Ps[ty * 4 + i][tx * 4]) = pv;
            if (tx == 0) alphas[ty * 4 + i] = alpha;
        }
        __syncthreads();               // Ps/alphas visible

        // ---- O update: o[r_o][c0..c0+11] = o*alpha + P[r_o,:] @ V[:,c] ----
        float al = alphas[r_o];
        #pragma unroll
        for (int c = 0; c < 12; ++c) o[c] *= al;
        #pragma unroll 4
        for (int j = 0; j < 64; j += 4) {
            float4 p4 = *reinterpret_cast<const float4*>(&Ps[r_o][j]);
            float pj[4] = {p4.x, p4.y, p4.z, p4.w};
            #pragma unroll
            for (int u = 0; u < 4; ++u) {
                #pragma unroll
                for (int cc = 0; cc < 3; ++cc) {
                    float4 v4 = *reinterpret_cast<const float4*>(&Vs[j + u][c0 + cc * 4]);
                    o[cc * 4 + 0] = fmaf(pj[u], v4.x, o[cc * 4 + 0]);
                    o[cc * 4 + 1] = fmaf(pj[u], v4.y, o[cc * 4 + 1]);
                    o[cc * 4 + 2] = fmaf(pj[u], v4.z, o[cc * 4 + 2]);
                    o[cc * 4 + 3] = fmaf(pj[u], v4.w, o[cc * 4 + 3]);
                }
            }
        }
    }

    // ---- finalize: divide by l, store ----
    if (tx == 0) {
        #pragma unroll
        for (int i = 0; i < 4; ++i) ls[ty * 4 + i] = l_i[i];
    }
    __syncthreads();
    float inv = 1.0f / ls[r_o];
    #pragma unroll
    for (int cc = 0; cc < 3; ++cc) {
        float4 ov;
        ov.x = o[cc * 4 + 0] * inv;
        ov.y = o[cc * 4 + 1] * inv;
        ov.z = o[cc * 4 + 2] * inv;
        ov.w = o[cc * 4 + 3] * inv;
        *reinterpret_cast<float4*>(AO + base + (size_t)(q0 + r_o) * E_ + c0 + cc * 4) = ov;
    }
}

// ---------------------------------------------------------------------------
extern "C" void kernel_launch(void* const* d_in, const int* in_sizes, int n_in,
                              void* d_out, int out_size, void* d_ws, size_t ws_size,
                              hipStream_t stream) {
    (void)in_sizes; (void)n_in; (void)out_size; (void)ws_size;
    const float* x    = (const float*)d_in[0];
    const int*   mask = (const int*)  d_in[1];   // bool -> int32 per harness convention
    const float* Wq   = (const float*)d_in[2];
    const float* bq   = (const float*)d_in[3];
    const float* Wk   = (const float*)d_in[4];
    const float* bk   = (const float*)d_in[5];
    const float* Wv   = (const float*)d_in[6];
    const float* bv   = (const float*)d_in[7];
    const float* Wo   = (const float*)d_in[8];
    const float* bo   = (const float*)d_in[9];

    float* ws = (float*)d_ws;
    const size_t NELEM = (size_t)M_ * E_;        // 3,145,728 floats
    float* Q  = ws;
    float* Kb = ws + NELEM;
    float* Vb = ws + 2 * NELEM;
    float* AO = ws + 3 * NELEM;

    dim3 blk(256);
    dim3 gproj(M_ / 64, E_ / 64);                // (128, 6)
    gemm64<<<gproj, blk, 0, stream>>>(x, Wq, bq, Q);
    gemm64<<<gproj, blk, 0, stream>>>(x, Wk, bk, Kb);
    gemm64<<<gproj, blk, 0, stream>>>(x, Wv, bv, Vb);

    dim3 gattn(S_ / 64, B_ * H_);                // (32, 32)
    attn<<<gattn, blk, 0, stream>>>(Q, Kb, Vb, mask, AO);

    gemm64<<<gproj, blk, 0, stream>>>(AO, Wo, bo, (float*)d_out);
}

// Round 2
// 328.021 us; speedup vs baseline: 2.8074x; 2.8074x over previous
//
#include <hip/hip_runtime.h>
#include <math.h>

// Problem constants (reference: B=4, S=2048, E=384, H=8, D=48)
#define B_ 4
#define S_ 2048
#define E_ 384
#define H_ 8
#define D_ 48
#define M_ (B_*S_)            // 8192 rows
constexpr float SCALE = 0.14433756729740643f;           // 1/sqrt(48)
constexpr float QK_SCALE = 0.14433756729740643f * 1.4426950408889634f; // fold log2e: use exp2

typedef __attribute__((ext_vector_type(8))) short short8;   // 8 bf16 = 4 VGPRs
typedef __attribute__((ext_vector_type(4))) float f32x4;

__device__ inline unsigned short f2bf(float f) {            // RNE fp32->bf16
    unsigned u = __float_as_uint(f);
    return (unsigned short)((u + 0x7FFFu + ((u >> 16) & 1u)) >> 16);
}
__device__ inline unsigned pk2(float a, float b) {
    return (unsigned)f2bf(a) | ((unsigned)f2bf(b) << 16);
}

// ---------------------------------------------------------------------------
// GEMM: C[M,384] = A[M,384] @ W[384,384]^T + bias  (fp32 SIMT, unchanged R1)
// ---------------------------------------------------------------------------
__global__ __launch_bounds__(256) void gemm64(const float* __restrict__ A,
                                              const float* __restrict__ W,
                                              const float* __restrict__ bias,
                                              float* __restrict__ C) {
    __shared__ __align__(16) float As[16][68];
    __shared__ __align__(16) float Bs[16][68];
    const int t  = threadIdx.x;
    const int tx = t & 15, ty = t >> 4;
    const int m0 = blockIdx.x * 64, n0 = blockIdx.y * 64;
    const int lm = t >> 2;
    const int lk = (t & 3) * 4;

    float acc[4][4] = {};
    for (int kk = 0; kk < 384; kk += 16) {
        float4 a = *reinterpret_cast<const float4*>(A + (size_t)(m0 + lm) * 384 + kk + lk);
        float4 w = *reinterpret_cast<const float4*>(W + (size_t)(n0 + lm) * 384 + kk + lk);
        __syncthreads();
        As[lk + 0][lm] = a.x; As[lk + 1][lm] = a.y;
        As[lk + 2][lm] = a.z; As[lk + 3][lm] = a.w;
        Bs[lk + 0][lm] = w.x; Bs[lk + 1][lm] = w.y;
        Bs[lk + 2][lm] = w.z; Bs[lk + 3][lm] = w.w;
        __syncthreads();
        #pragma unroll
        for (int k = 0; k < 16; ++k) {
            float4 av = *reinterpret_cast<const float4*>(&As[k][ty * 4]);
            float4 bv = *reinterpret_cast<const float4*>(&Bs[k][tx * 4]);
            float aa[4] = {av.x, av.y, av.z, av.w};
            float bb[4] = {bv.x, bv.y, bv.z, bv.w};
            #pragma unroll
            for (int i = 0; i < 4; ++i)
                #pragma unroll
                for (int j = 0; j < 4; ++j)
                    acc[i][j] = fmaf(aa[i], bb[j], acc[i][j]);
        }
    }
    #pragma unroll
    for (int i = 0; i < 4; ++i) {
        float4 o;
        o.x = acc[i][0] + bias[n0 + tx * 4 + 0];
        o.y = acc[i][1] + bias[n0 + tx * 4 + 1];
        o.z = acc[i][2] + bias[n0 + tx * 4 + 2];
        o.w = acc[i][3] + bias[n0 + tx * 4 + 3];
        *reinterpret_cast<float4*>(C + (size_t)(m0 + ty * 4 + i) * 384 + n0 + tx * 4) = o;
    }
}

// ---------------------------------------------------------------------------
// MFMA flash attention (bf16 matmuls, fp32 softmax).
// Block = 256 threads = 4 waves; wave owns 32 q-rows (2 N-tiles of 16).
// Block covers 128 q-rows of one (b,h); K/V staged in 64-key tiles.
// S^T = K·Q^T so P exits in reg-contiguous-key layout -> b64 pack into
// Ps[q][key], which is the PV A-operand layout. Q LDS reused as Ps.
// ---------------------------------------------------------------------------
__global__ __launch_bounds__(256) void attn_mfma(const float* __restrict__ Qg,
                                                 const float* __restrict__ Kg,
                                                 const float* __restrict__ Vg,
                                                 const int*   __restrict__ mask,
                                                 float* __restrict__ AO) {
    __shared__ __align__(16) unsigned short QPs[128][72]; // Q (d 0..63, 48+ zero) then P[q][key]
    __shared__ __align__(16) unsigned short Ksh[64][72];  // K rows, d 0..63 (48+ zero)
    __shared__ __align__(16) unsigned short Vt[48][72];   // V^T: [d][key]
    __shared__ __align__(16) float msf[64];               // 0.0 (masked) / 1.0
    __shared__ __align__(16) float axl[4][32];            // per-wave alpha / 1/l bounce

    const int t    = threadIdx.x;
    const int w    = t >> 6;
    const int lane = t & 63;
    const int ln   = lane & 15;
    const int quad = lane >> 4;
    const int q0   = blockIdx.x * 128;
    const int bh   = blockIdx.y;
    const int b    = bh >> 3, h = bh & 7;
    const int cb   = h * 48;                      // column base within E
    const size_t rb = (size_t)b * S_;             // row base

    // ---- stage Q (scaled by QK_SCALE), zero d-pad for Q and K ----
    {
        const int r = t >> 1, hf = t & 1;
        const float* src = Qg + (rb + q0 + r) * E_ + cb + hf * 24;
        unsigned short* dst = &QPs[r][hf * 24];
        #pragma unroll
        for (int i = 0; i < 6; ++i) {
            float4 v = reinterpret_cast<const float4*>(src)[i];
            uint2 p; p.x = pk2(v.x * QK_SCALE, v.y * QK_SCALE);
            p.y = pk2(v.z * QK_SCALE, v.w * QK_SCALE);
            *reinterpret_cast<uint2*>(dst + i * 4) = p;
        }
        uint4 z = {0, 0, 0, 0};
        *reinterpret_cast<uint4*>(&QPs[r][48 + hf * 8]) = z;   // Q d-pad
        if (t < 128) {
            int rr = t >> 1, hh = t & 1;
            *reinterpret_cast<uint4*>(&Ksh[rr][48 + hh * 8]) = z; // K d-pad (persists)
        }
    }
    __syncthreads();

    // ---- hoist Q B-fragments (wave's 32 q-rows, 2 k-steps) ----
    short8 qf[2][2];
    #pragma unroll
    for (int qt = 0; qt < 2; ++qt)
        #pragma unroll
        for (int ks = 0; ks < 2; ++ks)
            qf[qt][ks] = *reinterpret_cast<const short8*>(&QPs[w * 32 + qt * 16 + ln][ks * 32 + quad * 8]);

    f32x4 o[2][3];
    #pragma unroll
    for (int qt = 0; qt < 2; ++qt)
        #pragma unroll
        for (int nt = 0; nt < 3; ++nt)
            o[qt][nt] = (f32x4){0.f, 0.f, 0.f, 0.f};
    float mq[2] = {-INFINITY, -INFINITY};
    float lq[2] = {0.f, 0.f};

    for (int kt = 0; kt < S_ / 64; ++kt) {
        const int k0 = kt * 64;
        __syncthreads();   // prev tile's readers of Ksh/Vt/msf done (also gates Q-hoist vs P-write)

        // ---- stage K (bf16 rows) and V (transposed) ----
        {
            const int r = t >> 2, qd = t & 3;
            const float* ksrc = Kg + (rb + k0 + r) * E_ + cb + qd * 12;
            unsigned short* kdst = &Ksh[r][qd * 12];
            #pragma unroll
            for (int i = 0; i < 3; ++i) {
                float4 v = reinterpret_cast<const float4*>(ksrc)[i];
                uint2 p; p.x = pk2(v.x, v.y); p.y = pk2(v.z, v.w);
                *reinterpret_cast<uint2*>(kdst + i * 4) = p;
            }
            const float* vsrc = Vg + (rb + k0 + r) * E_ + cb + qd * 12;
            #pragma unroll
            for (int i = 0; i < 3; ++i) {
                float4 v = reinterpret_cast<const float4*>(vsrc)[i];
                int d0 = qd * 12 + i * 4;
                Vt[d0 + 0][r] = f2bf(v.x);
                Vt[d0 + 1][r] = f2bf(v.y);
                Vt[d0 + 2][r] = f2bf(v.z);
                Vt[d0 + 3][r] = f2bf(v.w);
            }
            if (t < 64) msf[t] = mask[(size_t)b * S_ + k0 + t] ? 0.0f : 1.0f;
        }
        __syncthreads();

        // ---- S^T = K·Q^T : D[key][q], 4 key-tiles x 2 q-tiles ----
        f32x4 sc[4][2];
        #pragma unroll
        for (int Mt = 0; Mt < 4; ++Mt) {
            short8 kf0 = *reinterpret_cast<const short8*>(&Ksh[Mt * 16 + ln][quad * 8]);
            short8 kf1 = *reinterpret_cast<const short8*>(&Ksh[Mt * 16 + ln][32 + quad * 8]);
            #pragma unroll
            for (int qt = 0; qt < 2; ++qt) {
                f32x4 acc = __builtin_amdgcn_mfma_f32_16x16x32_bf16(kf0, qf[qt][0], (f32x4){0.f,0.f,0.f,0.f}, 0, 0, 0);
                sc[Mt][qt]  = __builtin_amdgcn_mfma_f32_16x16x32_bf16(kf1, qf[qt][1], acc, 0, 0, 0);
            }
        }

        // mask multipliers for this lane's 16 keys (4 per key-tile, consecutive)
        f32x4 mm[4];
        #pragma unroll
        for (int Mt = 0; Mt < 4; ++Mt)
            mm[Mt] = *reinterpret_cast<const f32x4*>(&msf[Mt * 16 + quad * 4]);

        // ---- online softmax per q-tile; pack P -> Ps[q][key] ----
        #pragma unroll
        for (int qt = 0; qt < 2; ++qt) {
            float tmax = -INFINITY;
            #pragma unroll
            for (int Mt = 0; Mt < 4; ++Mt)
                #pragma unroll
                for (int r = 0; r < 4; ++r)
                    tmax = fmaxf(tmax, sc[Mt][qt][r]);
            tmax = fmaxf(tmax, __shfl_xor(tmax, 16));
            tmax = fmaxf(tmax, __shfl_xor(tmax, 32));
            float mnew = fmaxf(mq[qt], tmax);
            float am   = exp2f(mq[qt] - mnew);
            float lsum = 0.f;
            const int qrow = w * 32 + qt * 16 + ln;
            #pragma unroll
            for (int Mt = 0; Mt < 4; ++Mt) {
                float p0 = exp2f(sc[Mt][qt][0] - mnew) * mm[Mt][0];
                float p1 = exp2f(sc[Mt][qt][1] - mnew) * mm[Mt][1];
                float p2 = exp2f(sc[Mt][qt][2] - mnew) * mm[Mt][2];
                float p3 = exp2f(sc[Mt][qt][3] - mnew) * mm[Mt][3];
                lsum += (p0 + p1) + (p2 + p3);
                uint2 pk; pk.x = pk2(p0, p1); pk.y = pk2(p2, p3);
                *reinterpret_cast<uint2*>(&QPs[qrow][Mt * 16 + quad * 4]) = pk;
            }
            lsum += __shfl_xor(lsum, 16);
            lsum += __shfl_xor(lsum, 32);
            lq[qt] = lq[qt] * am + lsum;
            mq[qt] = mnew;
            axl[w][qt * 16 + ln] = am;     // all quads write same value: benign
        }

        // ---- rescale O by alpha (read via LDS bounce, rows are reg-dim) ----
        #pragma unroll
        for (int qt = 0; qt < 2; ++qt) {
            f32x4 a4 = *reinterpret_cast<const f32x4*>(&axl[w][qt * 16 + quad * 4]);
            #pragma unroll
            for (int nt = 0; nt < 3; ++nt)
                #pragma unroll
                for (int r = 0; r < 4; ++r)
                    o[qt][nt][r] *= a4[r];
        }

        // ---- PV: O[q][d] += P·V ----
        short8 pa[2][2];
        #pragma unroll
        for (int qt = 0; qt < 2; ++qt)
            #pragma unroll
            for (int ks = 0; ks < 2; ++ks)
                pa[qt][ks] = *reinterpret_cast<const short8*>(&QPs[w * 32 + qt * 16 + ln][ks * 32 + quad * 8]);
        #pragma unroll
        for (int nt = 0; nt < 3; ++nt) {
            short8 vb0 = *reinterpret_cast<const short8*>(&Vt[nt * 16 + ln][quad * 8]);
            short8 vb1 = *reinterpret_cast<const short8*>(&Vt[nt * 16 + ln][32 + quad * 8]);
            #pragma unroll
            for (int qt = 0; qt < 2; ++qt) {
                o[qt][nt] = __builtin_amdgcn_mfma_f32_16x16x32_bf16(pa[qt][0], vb0, o[qt][nt], 0, 0, 0);
                o[qt][nt] = __builtin_amdgcn_mfma_f32_16x16x32_bf16(pa[qt][1], vb1, o[qt][nt], 0, 0, 0);
            }
        }
    }

    // ---- epilogue: divide by l, store ----
    #pragma unroll
    for (int qt = 0; qt < 2; ++qt)
        axl[w][qt * 16 + ln] = 1.0f / lq[qt];
    #pragma unroll
    for (int qt = 0; qt < 2; ++qt) {
        f32x4 il = *reinterpret_cast<const f32x4*>(&axl[w][qt * 16 + quad * 4]);
        #pragma unroll
        for (int nt = 0; nt < 3; ++nt)
            #pragma unroll
            for (int r = 0; r < 4; ++r) {
                size_t row = rb + q0 + w * 32 + qt * 16 + quad * 4 + r;
                AO[row * E_ + cb + nt * 16 + ln] = o[qt][nt][r] * il[r];
            }
    }
}

// ---------------------------------------------------------------------------
extern "C" void kernel_launch(void* const* d_in, const int* in_sizes, int n_in,
                              void* d_out, int out_size, void* d_ws, size_t ws_size,
                              hipStream_t stream) {
    (void)in_sizes; (void)n_in; (void)out_size; (void)ws_size;
    const float* x    = (const float*)d_in[0];
    const int*   mask = (const int*)  d_in[1];
    const float* Wq   = (const float*)d_in[2];
    const float* bq   = (const float*)d_in[3];
    const float* Wk   = (const float*)d_in[4];
    const float* bk   = (const float*)d_in[5];
    const float* Wv   = (const float*)d_in[6];
    const float* bv   = (const float*)d_in[7];
    const float* Wo   = (const float*)d_in[8];
    const float* bo   = (const float*)d_in[9];

    float* ws = (float*)d_ws;
    const size_t NELEM = (size_t)M_ * E_;
    float* Q  = ws;
    float* Kb = ws + NELEM;
    float* Vb = ws + 2 * NELEM;
    float* AO = ws + 3 * NELEM;

    dim3 blk(256);
    dim3 gproj(M_ / 64, E_ / 64);
    gemm64<<<gproj, blk, 0, stream>>>(x, Wq, bq, Q);
    gemm64<<<gproj, blk, 0, stream>>>(x, Wk, bk, Kb);
    gemm64<<<gproj, blk, 0, stream>>>(x, Wv, bv, Vb);

    dim3 gattn(S_ / 128, B_ * H_);               // (16, 32)
    attn_mfma<<<gattn, blk, 0, stream>>>(Q, Kb, Vb, mask, AO);

    gemm64<<<gproj, blk, 0, stream>>>(AO, Wo, bo, (float*)d_out);
}

// Round 3
// 212.224 us; speedup vs baseline: 4.3393x; 1.5456x over previous
//
#include <hip/hip_runtime.h>
#include <math.h>

// Problem constants (reference: B=4, S=2048, E=384, H=8, D=48)
#define B_ 4
#define S_ 2048
#define E_ 384
#define H_ 8
#define D_ 48
#define M_ (B_*S_)            // 8192 rows
constexpr float QK_SCALE = 0.14433756729740643f * 1.4426950408889634f; // 1/sqrt(48) * log2(e)

typedef __attribute__((ext_vector_type(8))) short short8;   // 8 bf16 = 4 VGPRs
typedef __attribute__((ext_vector_type(4))) float f32x4;
typedef unsigned short u16;

__device__ inline u16 f2bf(float f) {            // RNE fp32->bf16
    unsigned u = __float_as_uint(f);
    return (u16)((u + 0x7FFFu + ((u >> 16) & 1u)) >> 16);
}
__device__ inline float bf2f(u16 h) { return __uint_as_float(((unsigned)h) << 16); }
__device__ inline unsigned pk2(float a, float b) {
    return (unsigned)f2bf(a) | ((unsigned)f2bf(b) << 16);
}
__device__ inline void glld16(const void* g, void* l) {
    __builtin_amdgcn_global_load_lds((const __attribute__((address_space(1))) unsigned int*)g,
                                     (__attribute__((address_space(3))) unsigned int*)l, 16, 0, 0);
}

// ---------------------------------------------------------------------------
// Convert fp32 -> bf16 hi/lo planes.  hi=bf16(v), lo=bf16(v-hi).
// ---------------------------------------------------------------------------
__global__ __launch_bounds__(256) void conv_x(const float4* __restrict__ src,
                                              uint2* __restrict__ hi,
                                              uint2* __restrict__ lo, int n4) {
    int i = blockIdx.x * 256 + threadIdx.x;
    if (i >= n4) return;
    float4 v = src[i];
    u16 h0 = f2bf(v.x), h1 = f2bf(v.y), h2 = f2bf(v.z), h3 = f2bf(v.w);
    uint2 H, L;
    H.x = (unsigned)h0 | ((unsigned)h1 << 16);
    H.y = (unsigned)h2 | ((unsigned)h3 << 16);
    L.x = pk2(v.x - bf2f(h0), v.y - bf2f(h1));
    L.y = pk2(v.z - bf2f(h2), v.w - bf2f(h3));
    hi[i] = H; lo[i] = L;
}

// All 4 weights (384x384 each) in one launch. out layout: [w][hi|lo][n4] uint2.
__global__ __launch_bounds__(256) void conv_w4(const float4* __restrict__ wq,
                                               const float4* __restrict__ wk,
                                               const float4* __restrict__ wv,
                                               const float4* __restrict__ wo,
                                               uint2* __restrict__ out, int n4) {
    int i = blockIdx.x * 256 + threadIdx.x;
    if (i >= n4) return;
    const float4* srcs[4] = {wq, wk, wv, wo};
    #pragma unroll
    for (int j = 0; j < 4; ++j) {
        float4 v = srcs[j][i];
        u16 h0 = f2bf(v.x), h1 = f2bf(v.y), h2 = f2bf(v.z), h3 = f2bf(v.w);
        uint2 H, L;
        H.x = (unsigned)h0 | ((unsigned)h1 << 16);
        H.y = (unsigned)h2 | ((unsigned)h3 << 16);
        L.x = pk2(v.x - bf2f(h0), v.y - bf2f(h1));
        L.y = pk2(v.z - bf2f(h2), v.w - bf2f(h3));
        out[(size_t)(j * 2 + 0) * n4 + i] = H;
        out[(size_t)(j * 2 + 1) * n4 + i] = L;
    }
}

// ---------------------------------------------------------------------------
// MFMA GEMM body: C[M,384] = A @ W^T + bias.  A,W as bf16 hi/lo planes.
// bf16x3: acc = AhWh + AlWh + AhWl (AlWl dropped, ~2^-17 rel).
// Tile 128m x 64n, BK=64, global_load_lds w/ XOR chunk swizzle.
// ---------------------------------------------------------------------------
template <bool BF16OUT>
__device__ __forceinline__ void gemm_body(const u16* __restrict__ xh, const u16* __restrict__ xl,
                                          const u16* __restrict__ wh, const u16* __restrict__ wl,
                                          const float* __restrict__ bias, float scale,
                                          u16* __restrict__ outb, float* __restrict__ outf,
                                          int m0, int n0) {
    __shared__ u16 As[2][128 * 64];   // [hi|lo][row*64 + slot*8], swizzled slot = chunk ^ (row&7)
    __shared__ u16 Ws[2][64 * 64];

    const int t = threadIdx.x, w = t >> 6, lane = t & 63;
    const int ln = lane & 15, quad = lane >> 4;
    const int gr = lane >> 3;             // staging sub-row 0..7
    const int gc = (lane & 7) ^ gr;       // swizzled source chunk

    f32x4 acc[2][4];
    #pragma unroll
    for (int mt = 0; mt < 2; ++mt)
        #pragma unroll
        for (int nt = 0; nt < 4; ++nt)
            acc[mt][nt] = (f32x4){0.f, 0.f, 0.f, 0.f};

    for (int kk = 0; kk < 384; kk += 64) {
        __syncthreads();                  // prior iter's frag reads done
        #pragma unroll
        for (int i = 0; i < 4; ++i) {     // A: wave w stages rows w*32 .. +32
            int r0 = w * 32 + i * 8;
            size_t goff = (size_t)(m0 + r0 + gr) * E_ + kk + gc * 8;
            glld16(xh + goff, &As[0][r0 * 64]);
            glld16(xl + goff, &As[1][r0 * 64]);
        }
        #pragma unroll
        for (int i = 0; i < 2; ++i) {     // W: wave w stages rows w*16 .. +16
            int r0 = w * 16 + i * 8;
            size_t goff = (size_t)(n0 + r0 + gr) * E_ + kk + gc * 8;
            glld16(wh + goff, &Ws[0][r0 * 64]);
            glld16(wl + goff, &Ws[1][r0 * 64]);
        }
        __syncthreads();                  // staging visible

        #pragma unroll
        for (int ks = 0; ks < 2; ++ks) {
            const int slot = (ks * 4 + quad) ^ (ln & 7);
            short8 ah[2], al[2], wfh[4], wfl[4];
            #pragma unroll
            for (int mt = 0; mt < 2; ++mt) {
                int row = w * 32 + mt * 16 + ln;
                ah[mt] = *reinterpret_cast<const short8*>(&As[0][row * 64 + slot * 8]);
                al[mt] = *reinterpret_cast<const short8*>(&As[1][row * 64 + slot * 8]);
            }
            #pragma unroll
            for (int nt = 0; nt < 4; ++nt) {
                int row = nt * 16 + ln;
                wfh[nt] = *reinterpret_cast<const short8*>(&Ws[0][row * 64 + slot * 8]);
                wfl[nt] = *reinterpret_cast<const short8*>(&Ws[1][row * 64 + slot * 8]);
            }
            #pragma unroll
            for (int mt = 0; mt < 2; ++mt)
                #pragma unroll
                for (int nt = 0; nt < 4; ++nt) {
                    acc[mt][nt] = __builtin_amdgcn_mfma_f32_16x16x32_bf16(ah[mt], wfh[nt], acc[mt][nt], 0, 0, 0);
                    acc[mt][nt] = __builtin_amdgcn_mfma_f32_16x16x32_bf16(al[mt], wfh[nt], acc[mt][nt], 0, 0, 0);
                    acc[mt][nt] = __builtin_amdgcn_mfma_f32_16x16x32_bf16(ah[mt], wfl[nt], acc[mt][nt], 0, 0, 0);
                }
        }
    }

    // epilogue: D[m = quad*4+r][n = ln] per 16x16 tile
    #pragma unroll
    for (int nt = 0; nt < 4; ++nt) {
        const int col = n0 + nt * 16 + ln;
        const float bc = bias[col];
        #pragma unroll
        for (int mt = 0; mt < 2; ++mt)
            #pragma unroll
            for (int r = 0; r < 4; ++r) {
                size_t row = (size_t)(m0 + w * 32 + mt * 16 + quad * 4 + r);
                float val = (acc[mt][nt][r] + bc) * scale;
                if (BF16OUT) outb[row * E_ + col] = f2bf(val);
                else         outf[row * E_ + col] = val;
            }
    }
}

// Fused QKV: grid (M/128, 18); y/6 selects weight, Q pre-scaled by QK_SCALE.
__global__ __launch_bounds__(256) void gemm_qkv(const u16* __restrict__ xh, const u16* __restrict__ xl,
                                                const u16* __restrict__ wplanes,
                                                const float* __restrict__ bq, const float* __restrict__ bk,
                                                const float* __restrict__ bv,
                                                u16* __restrict__ Qb, u16* __restrict__ Kb,
                                                u16* __restrict__ Vb) {
    const int y = blockIdx.y;
    const int wsel = y / 6;
    const int n0 = (y - wsel * 6) * 64;
    const u16* wh = wplanes + (size_t)wsel * 2 * 147456;
    const u16* wl = wh + 147456;
    const float* bias = (wsel == 0) ? bq : (wsel == 1) ? bk : bv;
    u16* outb = (wsel == 0) ? Qb : (wsel == 1) ? Kb : Vb;
    const float scale = (wsel == 0) ? QK_SCALE : 1.0f;
    gemm_body<true>(xh, xl, wh, wl, bias, scale, outb, nullptr, blockIdx.x * 128, n0);
}

// O-proj: grid (M/128, 6), fp32 output.
__global__ __launch_bounds__(256) void gemm_out(const u16* __restrict__ ah, const u16* __restrict__ al,
                                                const u16* __restrict__ wplanes,
                                                const float* __restrict__ bo, float* __restrict__ out) {
    const u16* wh = wplanes + (size_t)3 * 2 * 147456;
    const u16* wl = wh + 147456;
    gemm_body<false>(ah, al, wh, wl, bo, 1.0f, nullptr, out, blockIdx.x * 128, blockIdx.y * 64);
}

// ---------------------------------------------------------------------------
// MFMA flash attention (bf16 in, fp32 softmax). Inputs are bf16; Q pre-scaled.
// Output written as bf16 hi/lo planes for the O-proj GEMM.
// ---------------------------------------------------------------------------
__global__ __launch_bounds__(256) void attn_mfma(const u16* __restrict__ Qg,
                                                 const u16* __restrict__ Kg,
                                                 const u16* __restrict__ Vg,
                                                 const int*   __restrict__ mask,
                                                 u16* __restrict__ AOh,
                                                 u16* __restrict__ AOl) {
    __shared__ __align__(16) u16 QPs[128][72]; // Q (d 0..63, 48+ zero) then P[q][key]
    __shared__ __align__(16) u16 Ksh[64][72];  // K rows, d 0..63 (48+ zero)
    __shared__ __align__(16) u16 Vt[48][72];   // V^T: [d][key]
    __shared__ __align__(16) float msf[64];    // 0.0 (masked) / 1.0
    __shared__ __align__(16) float axl[4][32];

    const int t    = threadIdx.x;
    const int w    = t >> 6;
    const int lane = t & 63;
    const int ln   = lane & 15;
    const int quad = lane >> 4;
    const int q0   = blockIdx.x * 128;
    const int bh   = blockIdx.y;
    const int b    = bh >> 3, h = bh & 7;
    const int cb   = h * 48;
    const size_t rb = (size_t)b * S_;

    // ---- stage Q (plain copy, already scaled+bf16), zero d-pads ----
    {
        const int r = t >> 1, hf = t & 1;
        const u16* src = Qg + (rb + q0 + r) * E_ + cb + hf * 24;
        uint4* dst = reinterpret_cast<uint4*>(&QPs[r][hf * 24]);
        dst[0] = *reinterpret_cast<const uint4*>(src);
        dst[1] = *reinterpret_cast<const uint4*>(src + 8);
        dst[2] = *reinterpret_cast<const uint4*>(src + 16);
        uint4 z = {0, 0, 0, 0};
        *reinterpret_cast<uint4*>(&QPs[r][48 + hf * 8]) = z;
        if (t < 128) {
            int rr = t >> 1, hh = t & 1;
            *reinterpret_cast<uint4*>(&Ksh[rr][48 + hh * 8]) = z;
        }
    }
    __syncthreads();

    // ---- hoist Q B-fragments ----
    short8 qf[2][2];
    #pragma unroll
    for (int qt = 0; qt < 2; ++qt)
        #pragma unroll
        for (int ks = 0; ks < 2; ++ks)
            qf[qt][ks] = *reinterpret_cast<const short8*>(&QPs[w * 32 + qt * 16 + ln][ks * 32 + quad * 8]);

    f32x4 o[2][3];
    #pragma unroll
    for (int qt = 0; qt < 2; ++qt)
        #pragma unroll
        for (int nt = 0; nt < 3; ++nt)
            o[qt][nt] = (f32x4){0.f, 0.f, 0.f, 0.f};
    float mq[2] = {-INFINITY, -INFINITY};
    float lq[2] = {0.f, 0.f};

    for (int kt = 0; kt < S_ / 64; ++kt) {
        const int k0 = kt * 64;
        __syncthreads();

        // ---- stage K (copy) and V (transpose, no convert) ----
        {
            const int r = t >> 2, qd = t & 3;
            const u16* ksrc = Kg + (rb + k0 + r) * E_ + cb + qd * 12;
            uint2* kd = reinterpret_cast<uint2*>(&Ksh[r][qd * 12]);
            kd[0] = *reinterpret_cast<const uint2*>(ksrc);
            kd[1] = *reinterpret_cast<const uint2*>(ksrc + 4);
            kd[2] = *reinterpret_cast<const uint2*>(ksrc + 8);
            const u16* vsrc = Vg + (rb + k0 + r) * E_ + cb + qd * 12;
            #pragma unroll
            for (int i = 0; i < 6; ++i) {
                unsigned u = *reinterpret_cast<const unsigned*>(vsrc + i * 2);
                int d0 = qd * 12 + i * 2;
                Vt[d0 + 0][r] = (u16)(u & 0xffffu);
                Vt[d0 + 1][r] = (u16)(u >> 16);
            }
            if (t < 64) msf[t] = mask[(size_t)b * S_ + k0 + t] ? 0.0f : 1.0f;
        }
        __syncthreads();

        // ---- S^T = K·Q^T ----
        f32x4 sc[4][2];
        #pragma unroll
        for (int Mt = 0; Mt < 4; ++Mt) {
            short8 kf0 = *reinterpret_cast<const short8*>(&Ksh[Mt * 16 + ln][quad * 8]);
            short8 kf1 = *reinterpret_cast<const short8*>(&Ksh[Mt * 16 + ln][32 + quad * 8]);
            #pragma unroll
            for (int qt = 0; qt < 2; ++qt) {
                f32x4 a0 = __builtin_amdgcn_mfma_f32_16x16x32_bf16(kf0, qf[qt][0], (f32x4){0.f,0.f,0.f,0.f}, 0, 0, 0);
                sc[Mt][qt] = __builtin_amdgcn_mfma_f32_16x16x32_bf16(kf1, qf[qt][1], a0, 0, 0, 0);
            }
        }

        f32x4 mm[4];
        #pragma unroll
        for (int Mt = 0; Mt < 4; ++Mt)
            mm[Mt] = *reinterpret_cast<const f32x4*>(&msf[Mt * 16 + quad * 4]);

        // ---- online softmax; pack P -> QPs[q][key] ----
        #pragma unroll
        for (int qt = 0; qt < 2; ++qt) {
            float tmax = -INFINITY;
            #pragma unroll
            for (int Mt = 0; Mt < 4; ++Mt)
                #pragma unroll
                for (int r = 0; r < 4; ++r)
                    tmax = fmaxf(tmax, sc[Mt][qt][r]);
            tmax = fmaxf(tmax, __shfl_xor(tmax, 16));
            tmax = fmaxf(tmax, __shfl_xor(tmax, 32));
            float mnew = fmaxf(mq[qt], tmax);
            float am   = exp2f(mq[qt] - mnew);
            float lsum = 0.f;
            const int qrow = w * 32 + qt * 16 + ln;
            #pragma unroll
            for (int Mt = 0; Mt < 4; ++Mt) {
                float p0 = exp2f(sc[Mt][qt][0] - mnew) * mm[Mt][0];
                float p1 = exp2f(sc[Mt][qt][1] - mnew) * mm[Mt][1];
                float p2 = exp2f(sc[Mt][qt][2] - mnew) * mm[Mt][2];
                float p3 = exp2f(sc[Mt][qt][3] - mnew) * mm[Mt][3];
                lsum += (p0 + p1) + (p2 + p3);
                uint2 pk; pk.x = pk2(p0, p1); pk.y = pk2(p2, p3);
                *reinterpret_cast<uint2*>(&QPs[qrow][Mt * 16 + quad * 4]) = pk;
            }
            lsum += __shfl_xor(lsum, 16);
            lsum += __shfl_xor(lsum, 32);
            lq[qt] = lq[qt] * am + lsum;
            mq[qt] = mnew;
            axl[w][qt * 16 + ln] = am;
        }

        // ---- rescale O by alpha ----
        #pragma unroll
        for (int qt = 0; qt < 2; ++qt) {
            f32x4 a4 = *reinterpret_cast<const f32x4*>(&axl[w][qt * 16 + quad * 4]);
            #pragma unroll
            for (int nt = 0; nt < 3; ++nt)
                #pragma unroll
                for (int r = 0; r < 4; ++r)
                    o[qt][nt][r] *= a4[r];
        }

        // ---- PV ----
        short8 pa[2][2];
        #pragma unroll
        for (int qt = 0; qt < 2; ++qt)
            #pragma unroll
            for (int ks = 0; ks < 2; ++ks)
                pa[qt][ks] = *reinterpret_cast<const short8*>(&QPs[w * 32 + qt * 16 + ln][ks * 32 + quad * 8]);
        #pragma unroll
        for (int nt = 0; nt < 3; ++nt) {
            short8 vb0 = *reinterpret_cast<const short8*>(&Vt[nt * 16 + ln][quad * 8]);
            short8 vb1 = *reinterpret_cast<const short8*>(&Vt[nt * 16 + ln][32 + quad * 8]);
            #pragma unroll
            for (int qt = 0; qt < 2; ++qt) {
                o[qt][nt] = __builtin_amdgcn_mfma_f32_16x16x32_bf16(pa[qt][0], vb0, o[qt][nt], 0, 0, 0);
                o[qt][nt] = __builtin_amdgcn_mfma_f32_16x16x32_bf16(pa[qt][1], vb1, o[qt][nt], 0, 0, 0);
            }
        }
    }

    // ---- epilogue: divide by l, store as bf16 hi/lo planes ----
    #pragma unroll
    for (int qt = 0; qt < 2; ++qt)
        axl[w][qt * 16 + ln] = 1.0f / lq[qt];
    #pragma unroll
    for (int qt = 0; qt < 2; ++qt) {
        f32x4 il = *reinterpret_cast<const f32x4*>(&axl[w][qt * 16 + quad * 4]);
        #pragma unroll
        for (int nt = 0; nt < 3; ++nt)
            #pragma unroll
            for (int r = 0; r < 4; ++r) {
                size_t row = rb + q0 + w * 32 + qt * 16 + quad * 4 + r;
                size_t idx = row * E_ + cb + nt * 16 + ln;
                float val = o[qt][nt][r] * il[r];
                u16 hv = f2bf(val);
                AOh[idx] = hv;
                AOl[idx] = f2bf(val - bf2f(hv));
            }
    }
}

// ---------------------------------------------------------------------------
extern "C" void kernel_launch(void* const* d_in, const int* in_sizes, int n_in,
                              void* d_out, int out_size, void* d_ws, size_t ws_size,
                              hipStream_t stream) {
    (void)in_sizes; (void)n_in; (void)out_size; (void)ws_size;
    const float* x    = (const float*)d_in[0];
    const int*   mask = (const int*)  d_in[1];
    const float* Wq   = (const float*)d_in[2];
    const float* bq   = (const float*)d_in[3];
    const float* Wk   = (const float*)d_in[4];
    const float* bk   = (const float*)d_in[5];
    const float* Wv   = (const float*)d_in[6];
    const float* bv   = (const float*)d_in[7];
    const float* Wo   = (const float*)d_in[8];
    const float* bo   = (const float*)d_in[9];

    const size_t NELEM = (size_t)M_ * E_;        // 3,145,728
    const size_t WELEM = (size_t)E_ * E_;        // 147,456
    u16* ws = (u16*)d_ws;
    u16* xh      = ws;                            // NELEM
    u16* xl      = xh + NELEM;                    // NELEM
    u16* wplanes = xl + NELEM;                    // 4*2*WELEM
    u16* Qb      = wplanes + 8 * WELEM;           // NELEM (bf16, pre-scaled)
    u16* Kb      = Qb + NELEM;
    u16* Vb      = Kb + NELEM;
    u16* AOh     = Vb + NELEM;
    u16* AOl     = AOh + NELEM;

    dim3 blk(256);
    conv_w4<<<dim3((int)(WELEM / 4 / 256)), blk, 0, stream>>>(
        (const float4*)Wq, (const float4*)Wk, (const float4*)Wv, (const float4*)Wo,
        (uint2*)wplanes, (int)(WELEM / 4));
    conv_x<<<dim3((int)(NELEM / 4 / 256)), blk, 0, stream>>>(
        (const float4*)x, (uint2*)xh, (uint2*)xl, (int)(NELEM / 4));

    gemm_qkv<<<dim3(M_ / 128, 18), blk, 0, stream>>>(xh, xl, wplanes, bq, bk, bv, Qb, Kb, Vb);

    attn_mfma<<<dim3(S_ / 128, B_ * H_), blk, 0, stream>>>(Qb, Kb, Vb, mask, AOh, AOl);

    gemm_out<<<dim3(M_ / 128, 6), blk, 0, stream>>>(AOh, AOl, wplanes, bo, (float*)d_out);
}